// Round 9
// baseline (288.369 us; speedup 1.0000x reference)
//
#include <hip/hip_runtime.h>

// GCN forward: 4 x (X@W -> gather-normalize-scatter -> +b, ReLU) -> mean pool -> linear
// N=50000 nodes, E=800000 edges, D=64, L=4, G=64.
// R9: agg gather made L2-resident by feature-slicing. H row = 4 cache lines; slice j =
// feats 16j..16j+15 (one 64B line per row). agg grid = nodeblocks x 4 slices with
// slice = blockIdx%4: blockIdx->XCD is round-robin %8, so each XCD gathers only ONE
// 3.2MB slice -> fits 4MB per-XCD L2 (R8 FETCH was 82MB/dispatch vs 12.8MB table).
// Wave = 4 nodes x 16 feats; indices preloaded 16-ahead per group, __shfl broadcast;
// per-node adds strictly ascending (masked +0.0f is bitwise-safe) -> bitwise identical.
// Transform unfused again (needs full rows) -> standalone matmul per layer returns.
// NOTE: rocprof top-5 "fillBufferAligned 268MB" = harness d_ws poison, untimed; ignore.

#define D 64
#define BSHIFT 10                 // nodes per bucket = 1024
#define BNODES 1024
#define EPT 16                    // edges per thread in partition kernels
#define CB (256 * EPT)            // edges per block = 4096
#define SW(r, c4) ((c4) ^ (((r) >> 2) & 15))

// ---- setup: transpose all W (blocks 0..L-1) + zero bcnt (block L) --------

__global__ __launch_bounds__(256) void setup_kernel(
        const float* __restrict__ W, float* __restrict__ Wt,
        int* __restrict__ bcnt, int L) {
    int b = blockIdx.x;
    if (b < L) {
        const float* w = W + (size_t)b * D * D;
        float* wt = Wt + (size_t)b * D * D;
        for (int idx = threadIdx.x; idx < D * D; idx += 256) {
            int k = idx >> 6, c = idx & 63;
            wt[c * D + k] = w[idx];
        }
    } else {
        bcnt[threadIdx.x] = 0;
    }
}

// ---- CSR build: bucket partition ----------------------------------------

__global__ __launch_bounds__(256) void bucket_hist(
        const int* __restrict__ dst, int* __restrict__ bcnt, int e) {
    __shared__ int c[256];
    int t = threadIdx.x;
    c[t] = 0;
    __syncthreads();
    int base = blockIdx.x * CB;
    #pragma unroll
    for (int k = 0; k < EPT; ++k) {
        int i = base + t + k * 256;
        if (i < e) atomicAdd(&c[dst[i] >> BSHIFT], 1);
    }
    __syncthreads();
    if (c[t]) atomicAdd(&bcnt[t], c[t]);
}

__global__ __launch_bounds__(256) void bucket_scan(
        const int* __restrict__ bcnt, int* __restrict__ boff, int* __restrict__ bcur,
        int* __restrict__ row_start, int n, int e, int nb) {
    __shared__ int sh[256];
    int t = threadIdx.x;
    int c = (t < nb) ? bcnt[t] : 0;
    sh[t] = c;
    __syncthreads();
    for (int off = 1; off < 256; off <<= 1) {
        int vp = (t >= off) ? sh[t - off] : 0;
        __syncthreads();
        sh[t] += vp;
        __syncthreads();
    }
    int excl = sh[t] - c;
    if (t < nb) { boff[t] = excl; bcur[t] = excl; }
    if (t == 255) boff[nb] = sh[255];   // == e
    if (t == 0) row_start[n] = e;
}

__global__ __launch_bounds__(256) void bucket_scatter(
        const int* __restrict__ src, const int* __restrict__ dst,
        int* __restrict__ bcur, unsigned* __restrict__ eb, int e) {
    __shared__ int cB[256], gb[256], cur[256];
    int t = threadIdx.x;
    cB[t] = 0;
    __syncthreads();
    int base = blockIdx.x * CB;
    int ps[EPT], pd[EPT];
    #pragma unroll
    for (int k = 0; k < EPT; ++k) {
        int i = base + t + k * 256;
        if (i < e) {
            ps[k] = src[i];
            pd[k] = dst[i];
            atomicAdd(&cB[pd[k] >> BSHIFT], 1);
        } else {
            pd[k] = -1;
        }
    }
    __syncthreads();
    if (cB[t]) gb[t] = atomicAdd(&bcur[t], cB[t]);
    cur[t] = 0;
    __syncthreads();
    #pragma unroll
    for (int k = 0; k < EPT; ++k) {
        if (pd[k] >= 0) {
            int b = pd[k] >> BSHIFT;
            int p = atomicAdd(&cur[b], 1);
            eb[gb[b] + p] = (unsigned)(ps[k] & 0xFFFF) | ((unsigned)(pd[k] & (BNODES - 1)) << 16);
        }
    }
}

__global__ __launch_bounds__(BNODES) void build_csr(
        const unsigned* __restrict__ eb, const int* __restrict__ boff,
        int* __restrict__ row_start, float* __restrict__ dinv,
        int* __restrict__ csr_src, int n) {
    __shared__ int sh[BNODES];
    __shared__ int cur[BNODES];
    int b = blockIdx.x, t = threadIdx.x;
    int s = boff[b], e2 = boff[b + 1];
    sh[t] = 0;
    __syncthreads();
    for (int i = s + t; i < e2; i += BNODES) atomicAdd(&sh[eb[i] >> 16], 1);
    __syncthreads();
    int c = sh[t];
    __syncthreads();
    for (int off = 1; off < BNODES; off <<= 1) {
        int vp = (t >= off) ? sh[t - off] : 0;
        __syncthreads();
        sh[t] += vp;
        __syncthreads();
    }
    int a = sh[t] - c + s;                // absolute row offset
    int node = b * BNODES + t;
    if (node < n) {
        row_start[node] = a;
        dinv[node] = 1.0f / sqrtf((float)(c + 1));
    }
    cur[t] = a;
    __syncthreads();
    for (int i = s + t; i < e2; i += BNODES) {
        unsigned v = eb[i];
        int p = atomicAdd(&cur[v >> 16], 1);
        csr_src[p] = (int)(v & 0xFFFFu);
    }
}

// ---- per-layer: H' = dinv .* (X @ W), 4x4 register tile, swizzled LDS ----

__global__ __launch_bounds__(256, 3) void matmul_kernel(
        const float* __restrict__ X, const float* __restrict__ Wt,
        const float* __restrict__ dinv, float* __restrict__ H, int n) {
    __shared__ float4 Xs[64 * 16];   // 16 KB, swizzled
    __shared__ float4 Ws[64 * 16];   // 16 KB, swizzled (Wt rows = W cols)
    int t = threadIdx.x;
    int rowBase = blockIdx.x * 64;
    const float4* X4 = (const float4*)X;
    const float4* Wt4 = (const float4*)Wt;
    #pragma unroll
    for (int p = 0; p < 4; ++p) {
        int rl = (t >> 4) + 16 * p;
        int c4 = t & 15;
        int r = rowBase + rl;
        float4 v = make_float4(0.f, 0.f, 0.f, 0.f);
        if (r < n) v = X4[(size_t)r * 16 + c4];
        Xs[rl * 16 + SW(rl, c4)] = v;
        Ws[rl * 16 + SW(rl, c4)] = Wt4[rl * 16 + c4];
    }
    __syncthreads();
    int wv = t >> 6, lane = t & 63;
    int rg = lane >> 2, cg = lane & 3;
    int r0 = rg * 4;
    int c0 = wv * 16 + cg * 4;
    float acc[4][4] = {};
    #pragma unroll 2
    for (int k4 = 0; k4 < 16; ++k4) {
        float4 xv[4], wvv[4];
        #pragma unroll
        for (int i = 0; i < 4; ++i) xv[i] = Xs[(r0 + i) * 16 + SW(r0 + i, k4)];
        #pragma unroll
        for (int j = 0; j < 4; ++j) wvv[j] = Ws[(c0 + j) * 16 + SW(c0 + j, k4)];
        #pragma unroll
        for (int i = 0; i < 4; ++i)
            #pragma unroll
            for (int j = 0; j < 4; ++j) {
                acc[i][j] += xv[i].x * wvv[j].x;
                acc[i][j] += xv[i].y * wvv[j].y;
                acc[i][j] += xv[i].z * wvv[j].z;
                acc[i][j] += xv[i].w * wvv[j].w;
            }
    }
    #pragma unroll
    for (int i = 0; i < 4; ++i) {
        int r = rowBase + r0 + i;
        if (r < n) {
            float dr = dinv[r];
            float4 o = make_float4(dr * acc[i][0], dr * acc[i][1],
                                   dr * acc[i][2], dr * acc[i][3]);
            *(float4*)&H[(size_t)r * D + c0] = o;
        }
    }
}

// ---- per-layer: aggregate + bias + ReLU, feature-sliced ------------------
// slice = blockIdx%4 (XCD-pinned via round-robin %8): each XCD's L2 only holds
// its 3.2MB slice of H. Wave = 4 nodes x 16 feats; group g = lanes 16g..16g+15
// owns node v; indices preloaded 16-ahead by the group's lanes, __shfl broadcast.
// Per-node edge adds strictly ascending; masked adds are +0.0f (bitwise-safe).

__global__ __launch_bounds__(256) void agg_sliced(
        const float* __restrict__ H, const int* __restrict__ csr_src,
        const int* __restrict__ row_start, const float* __restrict__ dinv,
        const float* __restrict__ bias, float* __restrict__ out, int n) {
    int sl   = blockIdx.x & 3;           // feature slice (64B line of the row)
    int nblk = blockIdx.x >> 2;
    int wave = threadIdx.x >> 6, lane = threadIdx.x & 63;
    int g = lane >> 4, f = lane & 15;
    int v = nblk * 16 + wave * 4 + g;
    if (v >= n) return;                  // group lanes exit together; shfl stays in-group
    int col = sl * 16 + f;
    float dv = dinv[v];
    int s = row_start[v];
    int deg = row_start[v + 1] - s;
    float acc = H[((size_t)v << 6) + col];   // self term (H pre-scaled by dinv)
    int m1 = max(deg, __shfl_xor(deg, 16, 64));
    int dmax = max(m1, __shfl_xor(m1, 32, 64));  // wave-uniform
    for (int base = 0; base < dmax; base += 16) {
        int idx = 0;
        if (base + f < deg) idx = csr_src[s + base + f];   // 16 upcoming edges of group g
        #pragma unroll
        for (int ii = 0; ii < 16; ii += 4) {
            if (base + ii < dmax) {      // wave-uniform branch
                int u0 = __shfl(idx, g * 16 + ii + 0, 64);
                int u1 = __shfl(idx, g * 16 + ii + 1, 64);
                int u2 = __shfl(idx, g * 16 + ii + 2, 64);
                int u3 = __shfl(idx, g * 16 + ii + 3, 64);
                float h0 = H[((size_t)u0 << 6) + col];
                float h1 = H[((size_t)u1 << 6) + col];
                float h2 = H[((size_t)u2 << 6) + col];
                float h3 = H[((size_t)u3 << 6) + col];
                acc += (base + ii + 0 < deg) ? h0 : 0.0f;
                acc += (base + ii + 1 < deg) ? h1 : 0.0f;
                acc += (base + ii + 2 < deg) ? h2 : 0.0f;
                acc += (base + ii + 3 < deg) ? h3 : 0.0f;
            }
        }
    }
    out[((size_t)v << 6) + col] = fmaxf(dv * acc + bias[col], 0.f);
}

// ---- mean pool + final linear, one block (1024 thr) per graph ------------

__device__ __forceinline__ int lower_bound_g(const int* __restrict__ b, int n, int g) {
    int lo = 0, hi = n;
    while (lo < hi) { int m = (lo + hi) >> 1; if (b[m] < g) lo = m + 1; else hi = m; }
    return lo;
}

__global__ __launch_bounds__(1024) void pool_final(
        const float* __restrict__ X, const int* __restrict__ batch,
        const float* __restrict__ linW, const float* __restrict__ linb,
        float* __restrict__ out, int n) {
    __shared__ float sh[16][64];
    int g = blockIdx.x;
    int gs = lower_bound_g(batch, n, g);
    int ge = lower_bound_g(batch, n, g + 1);
    int wv = threadIdx.x >> 6, lane = threadIdx.x & 63;
    float acc = 0.f;
    for (int r = gs + wv; r < ge; r += 16)
        acc += X[(size_t)r * D + lane];
    sh[wv][lane] = acc;
    __syncthreads();
    if (wv == 0) {
        float tot = 0.f;
        #pragma unroll
        for (int i = 0; i < 16; ++i) tot += sh[i][lane];
        float cnt = fmaxf((float)(ge - gs), 1.f);
        float p = (tot / cnt) * linW[lane];
        #pragma unroll
        for (int off = 32; off > 0; off >>= 1) p += __shfl_down(p, off, 64);
        if (lane == 0) out[g] = p + linb[0];
    }
}

// ---- orchestration -------------------------------------------------------

extern "C" void kernel_launch(void* const* d_in, const int* in_sizes, int n_in,
                              void* d_out, int out_size, void* d_ws, size_t ws_size,
                              hipStream_t stream) {
    const float* x      = (const float*)d_in[0];  // [N,64]
    const float* conv_W = (const float*)d_in[1];  // [4,64,64]
    const float* conv_b = (const float*)d_in[2];  // [4,64]
    const float* lin_W  = (const float*)d_in[3];  // [64,1]
    const float* lin_b  = (const float*)d_in[4];  // [1]
    const int*   edge   = (const int*)d_in[5];    // [2,E]
    const int*   batch  = (const int*)d_in[6];    // [N]

    const int n = in_sizes[0] / D;
    const int e = in_sizes[5] / 2;
    const int L = in_sizes[1] / (D * D);          // 4
    const int G = out_size;

    const int* esrc = edge;
    const int* edst = edge + e;

    // workspace layout (256B aligned)
    char* ws = (char*)d_ws;
    size_t off = 0;
    auto alloc = [&](size_t bytes) -> void* {
        void* p = ws + off;
        off += (bytes + 255) & ~(size_t)255;
        return p;
    };
    const int nb = (n + BNODES - 1) / BNODES;     // buckets (49)
    int*   bcnt      = (int*)alloc(256 * 4);
    int*   boff      = (int*)alloc(257 * 4);
    int*   bcur      = (int*)alloc(256 * 4);
    float* dinv      = (float*)alloc((size_t)n * 4);
    int*   row_start = (int*)alloc((size_t)(n + 1) * 4);
    int*   csr_src   = (int*)alloc((size_t)e * 4);
    float* wtbuf     = (float*)alloc((size_t)L * D * D * 4);
    float* hbuf      = (float*)alloc((size_t)n * D * 4);
    float* xbuf      = (float*)alloc((size_t)n * D * 4);
    unsigned* eb     = (unsigned*)hbuf;           // alias: eb dead before matmul writes hbuf
    (void)ws_size;

    setup_kernel<<<L + 1, 256, 0, stream>>>(conv_W, wtbuf, bcnt, L);

    const int pb = (e + CB - 1) / CB;             // partition blocks (196)
    bucket_hist   <<<pb, 256, 0, stream>>>(edst, bcnt, e);
    bucket_scan   <<<1, 256, 0, stream>>>(bcnt, boff, bcur, row_start, n, e, nb);
    bucket_scatter<<<pb, 256, 0, stream>>>(esrc, edst, bcur, eb, e);
    build_csr     <<<nb, BNODES, 0, stream>>>(eb, boff, row_start, dinv, csr_src, n);

    const int ablocks = ((n + 15) / 16) * 4;      // nodeblocks x 4 slices

    const float* xin = x;
    for (int l = 0; l < L; ++l) {
        matmul_kernel<<<(n + 63) / 64, 256, 0, stream>>>(xin, wtbuf + (size_t)l * D * D,
                                                         dinv, hbuf, n);
        agg_sliced<<<ablocks, 256, 0, stream>>>(hbuf, csr_src, row_start, dinv,
                                                conv_b + (size_t)l * D, xbuf, n);
        xin = xbuf;
    }

    // pool + final linear (single kernel)
    pool_final<<<G, 1024, 0, stream>>>(xin, batch, lin_W, lin_b, (float*)d_out, n);
}